// Round 2
// baseline (1017.072 us; speedup 1.0000x reference)
//
#include <hip/hip_runtime.h>
#include <float.h>

// ---------------------------------------------------------------------------
// SeqGraphRepNetwork: BiSeqGCN (closed-form 2-msg softmax) -> LN1 -> MHA(4 heads)
// -> out_proj + resid -> LN2 -> FFN + resid -> masked mean pool.
// Packed [N,128] layout. Round 1: intermediates stored bf16 (manual RNE),
// fp32 compute. 4 aliased N*D bf16 buffers => ~118 MB workspace (round-0 crash
// suspected ws overflow at ~292 MB). ws_size guard: silent-fail (absmax blows
// up, no fault) if workspace is still too small -> diagnostic signal.
// ---------------------------------------------------------------------------

#define D 128
#define NHEAD 4
#define HD 32
#define MAXL 160

// ---- bf16 <-> f32 helpers (raw ushort storage, RNE) ------------------------
__device__ __forceinline__ float lo2f(unsigned u) {
    union { unsigned i; float f; } x; x.i = u << 16; return x.f;
}
__device__ __forceinline__ float hi2f(unsigned u) {
    union { unsigned i; float f; } x; x.i = u & 0xffff0000u; return x.f;
}
__device__ __forceinline__ unsigned short f2bf(float f) {
    union { float f; unsigned i; } x; x.f = f;
    unsigned r = x.i + 0x7fffu + ((x.i >> 16) & 1u);
    return (unsigned short)(r >> 16);
}
__device__ __forceinline__ unsigned pack2(float a, float b) {
    return (unsigned)f2bf(a) | ((unsigned)f2bf(b) << 16);
}
__device__ __forceinline__ float bf2f(unsigned short u) {
    union { unsigned i; float f; } x; x.i = (unsigned)u << 16; return x.f;
}

// ---- K0: c_src = a_src @ att_W, c_dst = a_dst @ att_W ----------------------
__global__ void prep_c(const float* __restrict__ att_W, const float* __restrict__ a_src,
                       const float* __restrict__ a_dst, float* __restrict__ c_src,
                       float* __restrict__ c_dst) {
    int p = threadIdx.x;  // 128 threads
    float s = 0.f, d = 0.f;
    for (int q = 0; q < D; q++) {
        float w = att_W[q * D + p];
        s += a_src[q] * w;
        d += a_dst[q] * w;
    }
    c_src[p] = s;
    c_dst[p] = d;
}

// ---- K1: t[b] = delta_dis_embs[b] . c_src ---------------------------------
__global__ void prep_t(const float* __restrict__ delta, const float* __restrict__ c_src,
                       float* __restrict__ tb) {
    int b = blockIdx.x;       // 512 buckets
    int l = threadIdx.x;      // 64 lanes
    const float* row = delta + (size_t)b * D;
    float s = row[l] * c_src[l] + row[l + 64] * c_src[l + 64];
    #pragma unroll
    for (int o = 32; o; o >>= 1) s += __shfl_down(s, o, 64);
    if (l == 0) tb[b] = s;
}

// ---- K2: transpose the 6 weight matrices to [k][c] layout (fp32) -----------
__global__ void transpose_w(const float* __restrict__ in_proj_w,
                            const float* __restrict__ out_proj_w,
                            const float* __restrict__ ffn_w1,
                            const float* __restrict__ ffn_w2,
                            float* __restrict__ wt) {
    int idx = blockIdx.x * blockDim.x + threadIdx.x;
    if (idx >= 6 * D * D) return;
    int m = idx >> 14;            // which matrix
    int within = idx & (D * D - 1);
    int k = within >> 7, c = within & (D - 1);
    const float* src;
    if (m == 0) src = in_proj_w;                 // Wq
    else if (m == 1) src = in_proj_w + D * D;    // Wk
    else if (m == 2) src = in_proj_w + 2 * D * D;// Wv
    else if (m == 3) src = out_proj_w;
    else if (m == 4) src = ffn_w1;
    else src = ffn_w2;
    wt[idx] = src[c * D + k];     // WT[m][k][c] = W[c][k]
}

// ---- K3: gather x = POI[sess_idx] (bf16), s1/s2 logit dots, session starts -
__global__ void node_gather(const float* __restrict__ POI, const int* __restrict__ sess_idx,
                            const int* __restrict__ node_pos, const int* __restrict__ batch_ids,
                            const float* __restrict__ c_src, const float* __restrict__ c_dst,
                            unsigned short* __restrict__ x, float* __restrict__ s1,
                            float* __restrict__ s2, int* __restrict__ starts, int N) {
    int n = blockIdx.x * 4 + (threadIdx.x >> 6);
    if (n >= N) return;
    int lane = threadIdx.x & 63;
    int row = sess_idx[n];
    float2 v = *(const float2*)(POI + (size_t)row * D + lane * 2);
    ((unsigned*)x)[(size_t)n * 64 + lane] = pack2(v.x, v.y);
    float ps = v.x * c_src[lane * 2] + v.y * c_src[lane * 2 + 1];
    float pd = v.x * c_dst[lane * 2] + v.y * c_dst[lane * 2 + 1];
    #pragma unroll
    for (int o = 32; o; o >>= 1) {
        ps += __shfl_down(ps, o, 64);
        pd += __shfl_down(pd, o, 64);
    }
    if (lane == 0) {
        s1[n] = ps;
        s2[n] = pd;
        if (node_pos[n] == 0) starts[batch_ids[n]] = n;
    }
}

// ---- K4: H_u[n] = softmax2 blend of x[n-1], x[n+1] (bf16 in/out) -----------
__global__ void hu_k(const unsigned short* __restrict__ x, const float* __restrict__ s1,
                     const float* __restrict__ s2, const float* __restrict__ tb,
                     const int* __restrict__ edge_dist, const int* __restrict__ batch_ids,
                     const int* __restrict__ node_pos, const int* __restrict__ lengths,
                     unsigned short* __restrict__ Hu, int N) {
    int idx = blockIdx.x * 256 + threadIdx.x;
    if (idx >= N * 32) return;
    int n = idx >> 5, d4 = idx & 31;   // 4 elems per thread
    int g = batch_ids[n], pos = node_pos[n], L = lengths[g];
    bool hasF = pos > 0;          // fwd msg from n-1, edge index (n-1)-g
    bool hasB = pos < L - 1;      // bwd msg from n+1
    float la = hasF ? (s1[n] + tb[edge_dist[n - 1 - g]]) : -FLT_MAX;
    float lb = hasB ? s2[n] : -FLT_MAX;
    float m = fmaxf(la, lb);
    float ea = hasF ? expf(la - m) : 0.f;
    float eb = hasB ? expf(lb - m) : 0.f;
    float inv = 1.f / (ea + eb + 1e-16f);
    float wa = ea * inv, wb = eb * inv;
    float r0 = 0.f, r1 = 0.f, r2 = 0.f, r3 = 0.f;
    if (hasF) {
        uint2 a = ((const uint2*)x)[(size_t)(n - 1) * 32 + d4];
        r0 = wa * lo2f(a.x); r1 = wa * hi2f(a.x);
        r2 = wa * lo2f(a.y); r3 = wa * hi2f(a.y);
    }
    if (hasB) {
        uint2 b = ((const uint2*)x)[(size_t)(n + 1) * 32 + d4];
        r0 += wb * lo2f(b.x); r1 += wb * hi2f(b.x);
        r2 += wb * lo2f(b.y); r3 += wb * hi2f(b.y);
    }
    ((uint2*)Hu)[(size_t)n * 32 + d4] = make_uint2(pack2(r0, r1), pack2(r2, r3));
}

// ---- LayerNorm (optional residual add), one wave per row (bf16 in/out) -----
__global__ void ln_k(const unsigned short* __restrict__ in, const unsigned short* __restrict__ resid,
                     const float* __restrict__ g, const float* __restrict__ b,
                     unsigned short* __restrict__ out, int N) {
    int n = blockIdx.x * 4 + (threadIdx.x >> 6);
    if (n >= N) return;
    int l = threadIdx.x & 63;
    unsigned u = ((const unsigned*)in)[(size_t)n * 64 + l];
    float vx = lo2f(u), vy = hi2f(u);
    if (resid) {
        unsigned r = ((const unsigned*)resid)[(size_t)n * 64 + l];
        vx += lo2f(r); vy += hi2f(r);
    }
    float s = vx + vy;
    float ss = vx * vx + vy * vy;
    #pragma unroll
    for (int o = 32; o; o >>= 1) {
        s += __shfl_xor(s, o, 64);
        ss += __shfl_xor(ss, o, 64);
    }
    float mu = s * (1.f / D);
    float var = ss * (1.f / D) - mu * mu;
    float rinv = rsqrtf(var + 1e-8f);
    float ox = (vx - mu) * rinv * g[l * 2] + b[l * 2];
    float oy = (vy - mu) * rinv * g[l * 2 + 1] + b[l * 2 + 1];
    ((unsigned*)out)[(size_t)n * 64 + l] = pack2(ox, oy);
}

// ---- GEMM: out[M,128](bf16) = A[M,128](bf16) @ W^T + bias (+resid)(relu?) --
// WT fp32 pre-transposed [k][c]. 64x64 tile, Kt=64, 256 threads, 4x4 micro.
__device__ __forceinline__ void fma4(float acc[4], float a, const float4& w) {
    acc[0] += a * w.x; acc[1] += a * w.y; acc[2] += a * w.z; acc[3] += a * w.w;
}

__launch_bounds__(256)
__global__ void gemm128(const unsigned short* __restrict__ A, const float* __restrict__ WT,
                        const float* __restrict__ bias, const unsigned short* __restrict__ resid,
                        unsigned short* __restrict__ out, int M, int doRelu) {
    __shared__ float As[64][68];   // +4 pad
    __shared__ float Ws[64][64];
    int r0 = blockIdx.x * 64, c0 = blockIdx.y * 64;
    int t = threadIdx.x;
    int tr = t >> 4, tc = t & 15;
    float acc[4][4];
    #pragma unroll
    for (int i = 0; i < 4; i++)
        #pragma unroll
        for (int j = 0; j < 4; j++) acc[i][j] = 0.f;

    for (int kt = 0; kt < D; kt += 64) {
        if (kt) __syncthreads();
        // stage A (bf16 -> f32): 512 chunks of 8 elems over 2 iters
        #pragma unroll
        for (int i = 0; i < 2; i++) {
            int idx8 = t + i * 256;
            int row = idx8 >> 3, c8 = (idx8 & 7) * 8;
            int gr = r0 + row;
            float* dst = &As[row][c8];
            if (gr < M) {
                uint4 u = *(const uint4*)(A + (size_t)gr * D + kt + c8);
                dst[0] = lo2f(u.x); dst[1] = hi2f(u.x);
                dst[2] = lo2f(u.y); dst[3] = hi2f(u.y);
                dst[4] = lo2f(u.z); dst[5] = hi2f(u.z);
                dst[6] = lo2f(u.w); dst[7] = hi2f(u.w);
            } else {
                #pragma unroll
                for (int j = 0; j < 8; j++) dst[j] = 0.f;
            }
        }
        // stage W (fp32): 1024 float4s over 4 iters
        #pragma unroll
        for (int i = 0; i < 4; i++) {
            int idx4 = t + i * 256;
            int row = idx4 >> 4, c4 = (idx4 & 15) * 4;
            *(float4*)&Ws[row][c4] = *(const float4*)(WT + (size_t)(kt + row) * D + c0 + c4);
        }
        __syncthreads();
        #pragma unroll
        for (int k = 0; k < 64; k += 4) {
            float4 a[4], w[4];
            #pragma unroll
            for (int i = 0; i < 4; i++) a[i] = *(const float4*)&As[4 * tr + i][k];
            #pragma unroll
            for (int kk = 0; kk < 4; kk++) w[kk] = *(const float4*)&Ws[k + kk][4 * tc];
            #pragma unroll
            for (int i = 0; i < 4; i++) {
                fma4(acc[i], a[i].x, w[0]);
                fma4(acc[i], a[i].y, w[1]);
                fma4(acc[i], a[i].z, w[2]);
                fma4(acc[i], a[i].w, w[3]);
            }
        }
    }
    float4 bb = *(const float4*)(bias + c0 + 4 * tc);
    #pragma unroll
    for (int i = 0; i < 4; i++) {
        int gr = r0 + 4 * tr + i;
        if (gr < M) {
            float o0 = acc[i][0] + bb.x, o1 = acc[i][1] + bb.y;
            float o2 = acc[i][2] + bb.z, o3 = acc[i][3] + bb.w;
            if (resid) {
                uint2 rr = *(const uint2*)(resid + (size_t)gr * D + c0 + 4 * tc);
                o0 += lo2f(rr.x); o1 += hi2f(rr.x);
                o2 += lo2f(rr.y); o3 += hi2f(rr.y);
            }
            if (doRelu) {
                o0 = fmaxf(o0, 0.f); o1 = fmaxf(o1, 0.f);
                o2 = fmaxf(o2, 0.f); o3 = fmaxf(o3, 0.f);
            }
            *(uint2*)(out + (size_t)gr * D + c0 + 4 * tc) = make_uint2(pack2(o0, o1), pack2(o2, o3));
        }
    }
}

// ---- Per-session per-head attention (bf16 q/k/v/ctx). ctx may alias q: -----
// block (g,h) reads only q[sess rows, h-slice] (each thread before its own
// write), K/V live in other buffers, distinct (g,h) slices are disjoint.
__launch_bounds__(192)
__global__ void attn_k(const unsigned short* __restrict__ qb, const unsigned short* __restrict__ kb,
                       const unsigned short* __restrict__ vb, const int* __restrict__ starts,
                       const int* __restrict__ lengths, unsigned short* __restrict__ ctx) {
    __shared__ float Ks[MAXL][HD];
    __shared__ float Vs[MAXL][HD];
    int g = blockIdx.x, h = blockIdx.y;
    int start = starts[g], L = lengths[g];
    int t = threadIdx.x;
    for (int idx8 = t; idx8 < L * 4; idx8 += 192) {
        int p = idx8 >> 2, d8 = (idx8 & 3) * 8;
        size_t goff = (size_t)(start + p) * D + h * HD + d8;
        uint4 ku = *(const uint4*)(kb + goff);
        uint4 vu = *(const uint4*)(vb + goff);
        float* kd = &Ks[p][d8];
        float* vd = &Vs[p][d8];
        kd[0] = lo2f(ku.x); kd[1] = hi2f(ku.x); kd[2] = lo2f(ku.y); kd[3] = hi2f(ku.y);
        kd[4] = lo2f(ku.z); kd[5] = hi2f(ku.z); kd[6] = lo2f(ku.w); kd[7] = hi2f(ku.w);
        vd[0] = lo2f(vu.x); vd[1] = hi2f(vu.x); vd[2] = lo2f(vu.y); vd[3] = hi2f(vu.y);
        vd[4] = lo2f(vu.z); vd[5] = hi2f(vu.z); vd[6] = lo2f(vu.w); vd[7] = hi2f(vu.w);
    }
    __syncthreads();
    if (t >= L) return;
    float qv[HD];
    #pragma unroll
    for (int d8 = 0; d8 < 4; d8++) {
        uint4 u = *(const uint4*)(qb + (size_t)(start + t) * D + h * HD + d8 * 8);
        float* q = &qv[d8 * 8];
        q[0] = lo2f(u.x); q[1] = hi2f(u.x); q[2] = lo2f(u.y); q[3] = hi2f(u.y);
        q[4] = lo2f(u.z); q[5] = hi2f(u.z); q[6] = lo2f(u.w); q[7] = hi2f(u.w);
    }
    const float scale = 0.17677669529663687f;  // 1/sqrt(32)
    float m = -FLT_MAX, l = 0.f;
    float acc[HD];
    #pragma unroll
    for (int d = 0; d < HD; d++) acc[d] = 0.f;
    for (int kk = 0; kk < L; kk++) {
        float s = 0.f;
        const float4* kr = (const float4*)Ks[kk];
        #pragma unroll
        for (int d4 = 0; d4 < 8; d4++) {
            float4 k4 = kr[d4];
            s += qv[4 * d4] * k4.x + qv[4 * d4 + 1] * k4.y
               + qv[4 * d4 + 2] * k4.z + qv[4 * d4 + 3] * k4.w;
        }
        s *= scale;
        float mn = fmaxf(m, s);
        float alpha = expf(m - mn);     // first iter: exp(-inf) = 0
        float p = expf(s - mn);
        l = l * alpha + p;
        const float4* vr = (const float4*)Vs[kk];
        #pragma unroll
        for (int d4 = 0; d4 < 8; d4++) {
            float4 v4 = vr[d4];
            acc[4 * d4]     = acc[4 * d4]     * alpha + p * v4.x;
            acc[4 * d4 + 1] = acc[4 * d4 + 1] * alpha + p * v4.y;
            acc[4 * d4 + 2] = acc[4 * d4 + 2] * alpha + p * v4.z;
            acc[4 * d4 + 3] = acc[4 * d4 + 3] * alpha + p * v4.w;
        }
        m = mn;
    }
    float invl = 1.f / l;
    #pragma unroll
    for (int d8 = 0; d8 < 4; d8++) {
        uint4 o;
        o.x = pack2(acc[8 * d8]     * invl, acc[8 * d8 + 1] * invl);
        o.y = pack2(acc[8 * d8 + 2] * invl, acc[8 * d8 + 3] * invl);
        o.z = pack2(acc[8 * d8 + 4] * invl, acc[8 * d8 + 5] * invl);
        o.w = pack2(acc[8 * d8 + 6] * invl, acc[8 * d8 + 7] * invl);
        *(uint4*)(ctx + (size_t)(start + t) * D + h * HD + d8 * 8) = o;
    }
}

// ---- masked mean pool (bf16 -> fp32 out) -----------------------------------
__global__ void pool_k(const unsigned short* __restrict__ fin, const int* __restrict__ starts,
                       const int* __restrict__ lengths, float* __restrict__ out) {
    int g = blockIdx.x, d = threadIdx.x;  // 128 threads
    int start = starts[g], L = lengths[g];
    float s = 0.f;
    for (int p = 0; p < L; p++) s += bf2f(fin[(size_t)(start + p) * D + d]);
    out[(size_t)g * D + d] = s / (float)L;
}

// ---------------------------------------------------------------------------
extern "C" void kernel_launch(void* const* d_in, const int* in_sizes, int n_in,
                              void* d_out, int out_size, void* d_ws, size_t ws_size,
                              hipStream_t stream) {
    const float* POI        = (const float*)d_in[0];
    const float* delta      = (const float*)d_in[1];
    const float* att_W      = (const float*)d_in[2];
    const float* a_src      = (const float*)d_in[3];
    const float* a_dst      = (const float*)d_in[4];
    const float* in_proj_w  = (const float*)d_in[5];
    const float* in_proj_b  = (const float*)d_in[6];
    const float* out_proj_w = (const float*)d_in[7];
    const float* out_proj_b = (const float*)d_in[8];
    const float* ln1_g      = (const float*)d_in[9];
    const float* ln1_b      = (const float*)d_in[10];
    const float* ln2_g      = (const float*)d_in[11];
    const float* ln2_b      = (const float*)d_in[12];
    const float* ffn_w1     = (const float*)d_in[13];
    const float* ffn_b1     = (const float*)d_in[14];
    const float* ffn_w2     = (const float*)d_in[15];
    const float* ffn_b2     = (const float*)d_in[16];
    const int* sess_idx     = (const int*)d_in[17];
    const int* edge_dist    = (const int*)d_in[18];
    const int* batch_ids    = (const int*)d_in[20];
    const int* node_pos     = (const int*)d_in[21];
    const int* lengths      = (const int*)d_in[22];

    int N = in_sizes[17];
    int B = in_sizes[22];

    // ---- workspace layout in BYTES, 256-aligned blocks ---------------------
    char* base = (char*)d_ws;
    size_t off = 0;
    auto alloc = [&](size_t bytes) { size_t c = off; off = (off + bytes + 255) & ~(size_t)255; return c; };
    size_t o_csrc  = alloc(D * 4);
    size_t o_cdst  = alloc(D * 4);
    size_t o_t     = alloc(512 * 4);
    size_t o_s1    = alloc((size_t)N * 4);
    size_t o_s2    = alloc((size_t)N * 4);
    size_t o_start = alloc((size_t)B * 4);
    size_t o_wt    = alloc(6 * D * D * 4);
    size_t nb      = (size_t)N * D * 2;          // one bf16 [N,128] buffer
    size_t o_A = alloc(nb);
    size_t o_B = alloc(nb);
    size_t o_C = alloc(nb);
    size_t o_D = alloc(nb);
    if (ws_size < off) return;   // diagnostic: silent fail (bad absmax), no GPU fault

    float* c_src = (float*)(base + o_csrc);
    float* c_dst = (float*)(base + o_cdst);
    float* tb    = (float*)(base + o_t);
    float* s1    = (float*)(base + o_s1);
    float* s2    = (float*)(base + o_s2);
    int*   starts = (int*)(base + o_start);
    float* wt    = (float*)(base + o_wt);
    unsigned short* bufA = (unsigned short*)(base + o_A);
    unsigned short* bufB = (unsigned short*)(base + o_B);
    unsigned short* bufC = (unsigned short*)(base + o_C);
    unsigned short* bufD = (unsigned short*)(base + o_D);

    // ---- pipeline ----------------------------------------------------------
    prep_c<<<1, 128, 0, stream>>>(att_W, a_src, a_dst, c_src, c_dst);
    prep_t<<<512, 64, 0, stream>>>(delta, c_src, tb);
    transpose_w<<<(6 * D * D + 255) / 256, 256, 0, stream>>>(in_proj_w, out_proj_w, ffn_w1, ffn_w2, wt);
    node_gather<<<(N + 3) / 4, 256, 0, stream>>>(POI, sess_idx, node_pos, batch_ids,
                                                 c_src, c_dst, bufA, s1, s2, starts, N); // x=A
    hu_k<<<(N * 32 + 255) / 256, 256, 0, stream>>>(bufA, s1, s2, tb, edge_dist, batch_ids,
                                                   node_pos, lengths, bufB, N);          // Hu=B
    ln_k<<<(N + 3) / 4, 256, 0, stream>>>(bufB, nullptr, ln1_g, ln1_b, bufC, N);         // Q=C

    dim3 gg((N + 63) / 64, 2);
    gemm128<<<gg, 256, 0, stream>>>(bufB, wt + 1 * D * D, in_proj_b + D,     nullptr, bufD, N, 0); // k=D
    gemm128<<<gg, 256, 0, stream>>>(bufB, wt + 2 * D * D, in_proj_b + 2 * D, nullptr, bufA, N, 0); // v=A (x dead)
    gemm128<<<gg, 256, 0, stream>>>(bufC, wt + 0 * D * D, in_proj_b + 0,     nullptr, bufB, N, 0); // q=B (Hu dead)

    attn_k<<<dim3(B, NHEAD), 192, 0, stream>>>(bufB, bufD, bufA, starts, lengths, bufB); // ctx=B (aliases q: safe)

    gemm128<<<gg, 256, 0, stream>>>(bufB, wt + 3 * D * D, out_proj_b, nullptr, bufD, N, 0); // tmp=D (k dead)
    ln_k<<<(N + 3) / 4, 256, 0, stream>>>(bufD, bufC, ln2_g, ln2_b, bufA, N);               // out2=A (v dead)
    gemm128<<<gg, 256, 0, stream>>>(bufA, wt + 4 * D * D, ffn_b1, nullptr, bufC, N, 1);     // hidden=C (Q dead)
    gemm128<<<gg, 256, 0, stream>>>(bufC, wt + 5 * D * D, ffn_b2, bufA, bufD, N, 0);        // fin=D
    pool_k<<<B, 128, 0, stream>>>(bufD, starts, lengths, (float*)d_out);
}